// Round 6
// baseline (46.030 us; speedup 1.0000x reference)
//
#include <hip/hip_runtime.h>

// out = f1>=0 ? f1*winMax9x9(f2pad) : f1*winMin9x9(f2pad)  (separable 9-window)
// Vertical-first van Herk on float2 column-pairs (global -> LDS), one lgkm-only
// barrier, horizontal van Herk on 8-col aligned segments with ds_read_b128 /
// float4 f1 loads / float4 stores. LDS 25.5 KB, TPB=384.

#define HH 38
#define WW 68
#define PLANE (HH * WW)    // 2584
#define ST 84              // LDS row stride (dwords): 4 pad | 68 data | 4 pad | 8 slack
#define TPB 384
#define NB (16 * 512)

#define BAR() do { asm volatile("s_waitcnt lgkmcnt(0)" ::: "memory"); \
                   __builtin_amdgcn_s_barrier();                      \
                   __builtin_amdgcn_sched_barrier(0); } while (0)

__global__ __launch_bounds__(TPB) void corr_vh4_kernel(
    const float* __restrict__ f1, const float* __restrict__ f2,
    float* __restrict__ out)
{
    __shared__ float hmx[HH * ST];   // vertical 9-window max, padded cols
    __shared__ float hmn[HH * ST];   // vertical 9-window min

    const int t = threadIdx.x;
    const int base = blockIdx.x * PLANE;
    const float* __restrict__ f2p = f2 + base;

    // ---- phase H decomposition: 38 rows x 9 segments of 8 output cols ----
    const int hr = t / 9, hs = t % 9;
    const int hc0 = (hs < 8) ? hs * 8 : 60;        // seg 8 overlaps seg 7 (same values)

    // ---- prefetch f1 (float4 x2), in flight across the barrier ----
    float4 fa, fb;
    if (t < 342) {
        fa = *reinterpret_cast<const float4*>(f1 + base + hr * WW + hc0);
        fb = *reinterpret_cast<const float4*>(f1 + base + hr * WW + hc0 + 4);
    }

    // ---- zero pad cols: phys 0..3 and 72..75, both planes (float4) ----
    if (t < 152) {                                  // 38 rows x {hmx,hmn} x {L,R}
        int row = t >> 2, q = t & 3;
        float* pl = (q & 2) ? hmn : hmx;
        *reinterpret_cast<float4*>(pl + row * ST + ((q & 1) ? 72 : 0)) =
            make_float4(0, 0, 0, 0);
    }

    // ---- vertical 9-window MAX+MIN via van Herk, float2 column pairs ----
    if (t < 136) {                                  // 34 col-pairs x 4 row-segments
        const int cp = t % 34, seg = t / 34;
        const int c2 = cp * 2;
        const int h0 = (seg == 3) ? 28 : seg * 10;  // overlap trick, rows h0..h0+9
        float2 v[18];
        #pragma unroll
        for (int i = 0; i < 18; ++i) {
            int row = h0 - 4 + i;
            v[i] = (row >= 0 && row < HH)
                 ? *reinterpret_cast<const float2*>(f2p + row * WW + c2)
                 : make_float2(0.0f, 0.0f);
        }
        float2 Sx[9], Sn[9];
        Sx[8] = v[8]; Sn[8] = v[8];
        #pragma unroll
        for (int i = 7; i >= 0; --i) {
            Sx[i] = make_float2(fmaxf(v[i].x, Sx[i+1].x), fmaxf(v[i].y, Sx[i+1].y));
            Sn[i] = make_float2(fminf(v[i].x, Sn[i+1].x), fminf(v[i].y, Sn[i+1].y));
        }
        *reinterpret_cast<float2*>(&hmx[h0 * ST + 4 + c2]) = Sx[0];
        *reinterpret_cast<float2*>(&hmn[h0 * ST + 4 + c2]) = Sn[0];
        float2 Px = v[9], Pn = v[9];
        #pragma unroll
        for (int k = 1; k <= 8; ++k) {              // out row h0+k, window v[k..k+8]
            *reinterpret_cast<float2*>(&hmx[(h0 + k) * ST + 4 + c2]) =
                make_float2(fmaxf(Sx[k].x, Px.x), fmaxf(Sx[k].y, Px.y));
            *reinterpret_cast<float2*>(&hmn[(h0 + k) * ST + 4 + c2]) =
                make_float2(fminf(Sn[k].x, Pn.x), fminf(Sn[k].y, Pn.y));
            if (k < 8) {
                Px = make_float2(fmaxf(Px.x, v[9 + k].x), fmaxf(Px.y, v[9 + k].y));
                Pn = make_float2(fminf(Pn.x, v[9 + k].x), fminf(Pn.y, v[9 + k].y));
            }
        }
        Px = make_float2(fmaxf(Px.x, v[17].x), fmaxf(Px.y, v[17].y));
        Pn = make_float2(fminf(Pn.x, v[17].x), fminf(Pn.y, v[17].y));
        *reinterpret_cast<float2*>(&hmx[(h0 + 9) * ST + 4 + c2]) = Px;  // window v[9..17]
        *reinterpret_cast<float2*>(&hmn[(h0 + 9) * ST + 4 + c2]) = Pn;
    }

    BAR();   // LDS ready; f1 float4 loads keep flying (no vmcnt drain)

    // ---- horizontal 9-window MAX+MIN via van Herk + combine + store ----
    if (t < 342) {
        float u[16], S[9], wx[8], wn[8], P;
        // max plane: u[i] = phys col hc0+i = real col hc0-4+i
        #pragma unroll
        for (int q = 0; q < 4; ++q)
            *reinterpret_cast<float4*>(&u[q * 4]) =
                *reinterpret_cast<const float4*>(&hmx[hr * ST + hc0 + q * 4]);
        S[8] = u[8];
        #pragma unroll
        for (int i = 7; i >= 0; --i) S[i] = fmaxf(u[i], S[i + 1]);
        wx[0] = S[0];
        P = u[9];
        #pragma unroll
        for (int k = 1; k < 8; ++k) {               // wx[k] = max(u[k..k+8])
            wx[k] = fmaxf(S[k], P);
            if (k < 7) P = fmaxf(P, u[9 + k]);
        }
        // min plane
        #pragma unroll
        for (int q = 0; q < 4; ++q)
            *reinterpret_cast<float4*>(&u[q * 4]) =
                *reinterpret_cast<const float4*>(&hmn[hr * ST + hc0 + q * 4]);
        S[8] = u[8];
        #pragma unroll
        for (int i = 7; i >= 0; --i) S[i] = fminf(u[i], S[i + 1]);
        wn[0] = S[0];
        P = u[9];
        #pragma unroll
        for (int k = 1; k < 8; ++k) {
            wn[k] = fminf(S[k], P);
            if (k < 7) P = fminf(P, u[9 + k]);
        }
        // combine with f1 and store as 2x float4
        float4 ra, rb;
        ra.x = fa.x * (fa.x >= 0.0f ? wx[0] : wn[0]);
        ra.y = fa.y * (fa.y >= 0.0f ? wx[1] : wn[1]);
        ra.z = fa.z * (fa.z >= 0.0f ? wx[2] : wn[2]);
        ra.w = fa.w * (fa.w >= 0.0f ? wx[3] : wn[3]);
        rb.x = fb.x * (fb.x >= 0.0f ? wx[4] : wn[4]);
        rb.y = fb.y * (fb.y >= 0.0f ? wx[5] : wn[5]);
        rb.z = fb.z * (fb.z >= 0.0f ? wx[6] : wn[6]);
        rb.w = fb.w * (fb.w >= 0.0f ? wx[7] : wn[7]);
        *reinterpret_cast<float4*>(out + base + hr * WW + hc0)     = ra;
        *reinterpret_cast<float4*>(out + base + hr * WW + hc0 + 4) = rb;
    }
}

extern "C" void kernel_launch(void* const* d_in, const int* in_sizes, int n_in,
                              void* d_out, int out_size, void* d_ws, size_t ws_size,
                              hipStream_t stream) {
    const float* f1 = (const float*)d_in[0];
    const float* f2 = (const float*)d_in[1];
    float* out = (float*)d_out;
    corr_vh4_kernel<<<dim3(NB), dim3(TPB), 0, stream>>>(f1, f2, out);
}

// Round 7
// 45.100 us; speedup vs baseline: 1.0206x; 1.0206x over previous
//
#include <hip/hip_runtime.h>

// out = f1>=0 ? f1*winMax9x9(f2pad) : f1*winMin9x9(f2pad)  (separable 9-window)
// 2 planes per block processed IN PARALLEL (not serial): phase V uses 340/384
// threads (both planes at once, 8-row van Herk segments), one lgkm-only
// barrier, phase H does both planes per thread (2x ILP behind every wait).
// LDS 46.2 KB -> 3 blocks/CU; block count halved to 4096.

#define HH 38
#define WW 68
#define PLANE (HH * WW)        // 2584
#define ST 76                  // LDS row stride: 4 pad | 68 data | 4 pad
#define TPB 384
#define PPB 2
#define NB ((16 * 512) / PPB)  // 4096

#define BAR() do { asm volatile("s_waitcnt lgkmcnt(0)" ::: "memory"); \
                   __builtin_amdgcn_s_barrier();                      \
                   __builtin_amdgcn_sched_barrier(0); } while (0)

__device__ __forceinline__ float2 f2max(float2 a, float2 b) {
    return make_float2(fmaxf(a.x, b.x), fmaxf(a.y, b.y));
}
__device__ __forceinline__ float2 f2min(float2 a, float2 b) {
    return make_float2(fminf(a.x, b.x), fminf(a.y, b.y));
}

__global__ __launch_bounds__(TPB) void corr_ilp2_kernel(
    const float* __restrict__ f1, const float* __restrict__ f2,
    float* __restrict__ out)
{
    __shared__ float hmx[PPB][HH * ST];   // vertical 9-window max per plane
    __shared__ float hmn[PPB][HH * ST];   // vertical 9-window min per plane

    const int t = threadIdx.x;
    const int base0 = blockIdx.x * (PPB * PLANE);

    // ---- phase H decomposition: 38 rows x 9 segs of 8 cols (seg 8 overlaps) ----
    const int hr = t / 9, hs = t % 9;
    const int hc0 = (hs < 8) ? hs * 8 : 60;
    const bool hAct = (t < 342);

    // ---- phase V decomposition: 2 planes x 5 row-segs x 34 col-pairs ----
    const int vp = t / 170, vj = t % 170;
    const int vcp = vj % 34, vseg = vj / 34;
    const int vc2 = vcp * 2;
    const int vh0 = (vseg < 4) ? vseg * 8 : 30;    // rows vh0..vh0+7 (seg 4 overlaps)
    const bool vAct = (t < 340);

    // ---- issue f2 loads (16 independent float2 per V-thread) ----
    float2 v[16];
    if (vAct) {
        const float* fp = f2 + base0 + vp * PLANE;
        #pragma unroll
        for (int i = 0; i < 16; ++i) {             // v[i] = row vh0-4+i
            int row = vh0 - 4 + i;
            v[i] = (row >= 0 && row < HH)
                 ? *reinterpret_cast<const float2*>(fp + row * WW + vc2)
                 : make_float2(0.0f, 0.0f);
        }
    }

    // ---- issue plane-0 f1 loads (consumed after barrier) ----
    float4 fa0, fb0;
    if (hAct) {
        fa0 = *reinterpret_cast<const float4*>(f1 + base0 + hr * WW + hc0);
        fb0 = *reinterpret_cast<const float4*>(f1 + base0 + hr * WW + hc0 + 4);
    }

    // ---- zero pad cols (phys 0..3, 72..75): 38 rows x 8 buf/side combos ----
    if (t < 304) {
        int row = t >> 3, q = t & 7;
        int side = q & 1, quant = (q >> 1) & 1, pl = q >> 2;
        float* b = quant ? hmn[pl] : hmx[pl];
        *reinterpret_cast<float4*>(b + row * ST + (side ? 72 : 0)) =
            make_float4(0, 0, 0, 0);
    }

    // ---- phase V: vertical 9-window max+min via van Herk, 8 outputs/thread ----
    if (vAct) {
        float* bx = hmx[vp];
        float* bn = hmn[vp];
        float2 S[9], P;
        // MAX: S[i] = max(v[i..8]); window k = v[k..k+8], k=0..7
        S[8] = v[8];
        #pragma unroll
        for (int i = 7; i >= 0; --i) S[i] = f2max(v[i], S[i + 1]);
        *reinterpret_cast<float2*>(bx + vh0 * ST + 4 + vc2) = S[0];
        P = v[9];
        #pragma unroll
        for (int k = 1; k < 8; ++k) {
            *reinterpret_cast<float2*>(bx + (vh0 + k) * ST + 4 + vc2) = f2max(S[k], P);
            if (k < 7) P = f2max(P, v[9 + k]);
        }
        // MIN
        S[8] = v[8];
        #pragma unroll
        for (int i = 7; i >= 0; --i) S[i] = f2min(v[i], S[i + 1]);
        *reinterpret_cast<float2*>(bn + vh0 * ST + 4 + vc2) = S[0];
        P = v[9];
        #pragma unroll
        for (int k = 1; k < 8; ++k) {
            *reinterpret_cast<float2*>(bn + (vh0 + k) * ST + 4 + vc2) = f2min(S[k], P);
            if (k < 7) P = f2min(P, v[9 + k]);
        }
    }

    BAR();   // LDS ready; f1 plane-0 loads keep flying (no vmcnt drain)

    // ---- issue plane-1 f1 loads; latency hides under plane-0 compute ----
    float4 fa1, fb1;
    if (hAct) {
        fa1 = *reinterpret_cast<const float4*>(f1 + base0 + PLANE + hr * WW + hc0);
        fb1 = *reinterpret_cast<const float4*>(f1 + base0 + PLANE + hr * WW + hc0 + 4);
    }

    // ---- phase H: horizontal 9-window max+min + combine, both planes ----
    #pragma unroll
    for (int p = 0; p < PPB; ++p) {
        if (hAct) {
            float u[16], S[9], wx[8], wn[8], P;
            // max plane: u[i] = phys col hc0+i = real col hc0-4+i
            #pragma unroll
            for (int q = 0; q < 4; ++q)
                *reinterpret_cast<float4*>(&u[q * 4]) =
                    *reinterpret_cast<const float4*>(&hmx[p][hr * ST + hc0 + q * 4]);
            S[8] = u[8];
            #pragma unroll
            for (int i = 7; i >= 0; --i) S[i] = fmaxf(u[i], S[i + 1]);
            wx[0] = S[0];
            P = u[9];
            #pragma unroll
            for (int k = 1; k < 8; ++k) {           // wx[k] = max(u[k..k+8])
                wx[k] = fmaxf(S[k], P);
                if (k < 7) P = fmaxf(P, u[9 + k]);
            }
            // min plane
            #pragma unroll
            for (int q = 0; q < 4; ++q)
                *reinterpret_cast<float4*>(&u[q * 4]) =
                    *reinterpret_cast<const float4*>(&hmn[p][hr * ST + hc0 + q * 4]);
            S[8] = u[8];
            #pragma unroll
            for (int i = 7; i >= 0; --i) S[i] = fminf(u[i], S[i + 1]);
            wn[0] = S[0];
            P = u[9];
            #pragma unroll
            for (int k = 1; k < 8; ++k) {
                wn[k] = fminf(S[k], P);
                if (k < 7) P = fminf(P, u[9 + k]);
            }
            // combine with f1 and store 2x float4
            float4 A = (p == 0) ? fa0 : fa1;
            float4 B = (p == 0) ? fb0 : fb1;
            float4 ra, rb;
            ra.x = A.x * (A.x >= 0.0f ? wx[0] : wn[0]);
            ra.y = A.y * (A.y >= 0.0f ? wx[1] : wn[1]);
            ra.z = A.z * (A.z >= 0.0f ? wx[2] : wn[2]);
            ra.w = A.w * (A.w >= 0.0f ? wx[3] : wn[3]);
            rb.x = B.x * (B.x >= 0.0f ? wx[4] : wn[4]);
            rb.y = B.y * (B.y >= 0.0f ? wx[5] : wn[5]);
            rb.z = B.z * (B.z >= 0.0f ? wx[6] : wn[6]);
            rb.w = B.w * (B.w >= 0.0f ? wx[7] : wn[7]);
            *reinterpret_cast<float4*>(out + base0 + p * PLANE + hr * WW + hc0)     = ra;
            *reinterpret_cast<float4*>(out + base0 + p * PLANE + hr * WW + hc0 + 4) = rb;
        }
    }
}

extern "C" void kernel_launch(void* const* d_in, const int* in_sizes, int n_in,
                              void* d_out, int out_size, void* d_ws, size_t ws_size,
                              hipStream_t stream) {
    const float* f1 = (const float*)d_in[0];
    const float* f2 = (const float*)d_in[1];
    float* out = (float*)d_out;
    corr_ilp2_kernel<<<dim3(NB), dim3(TPB), 0, stream>>>(f1, f2, out);
}